// Round 17
// baseline (458.999 us; speedup 1.0000x reference)
//
#include <hip/hip_runtime.h>
#include <stdint.h>

#define HID 128
#define NNODES 50000
#define NEDGES 800000
#define WPL 98304   // bf16 weight elems per layer in wt scratch
#define NPAD 50176  // padded node count (= 196*256 = 49*1024)

typedef __attribute__((ext_vector_type(8))) short short8;
typedef __attribute__((ext_vector_type(4))) float floatx4;

__device__ __forceinline__ float bf2f(unsigned short h) {
    union { unsigned int u; float f; } v; v.u = ((unsigned int)h) << 16; return v.f;
}
__device__ __forceinline__ unsigned short f2bf(float f) {
    union { float f; unsigned int u; } v; v.f = f;
    unsigned int u = v.u;
    return (unsigned short)((u + 0x7fffu + ((u >> 16) & 1u)) >> 16);
}

// ---- convert all layer weights to bf16, transposed to [n][k] for MFMA B-frags ----
// layout per layer l: [W1a^T 128x128 | W1b^T 128x128 | W2^T 128x128 | U1^T 128x256 | U2^T 128x128]
__global__ __launch_bounds__(256) void cvt_weights(
    const float* __restrict__ mW1, const float* __restrict__ mW2,
    const float* __restrict__ uW1, const float* __restrict__ uW2,
    unsigned short* __restrict__ wt)
{
    int id = blockIdx.x * 256 + threadIdx.x;
    int l = id / WPL;
    int r = id - l * WPL;
    float v;
    if (r < 16384)      { int n = r >> 7, k = r & 127;                v = mW1[(l*257 + k)*128 + n]; }
    else if (r < 32768) { int q = r - 16384; int n = q >> 7, k = q & 127; v = mW1[(l*257 + 128 + k)*128 + n]; }
    else if (r < 49152) { int q = r - 32768; int n = q >> 7, k = q & 127; v = mW2[(l*128 + k)*128 + n]; }
    else if (r < 81920) { int q = r - 49152; int n = q >> 8, k = q & 255; v = uW1[(l*256 + k)*128 + n]; }
    else                { int q = r - 81920; int n = q >> 7, k = q & 127; v = uW2[(l*128 + k)*128 + n]; }
    wt[id] = f2bf(v);
}

// ---- prep (MFMA): wt2[l] = (W2@U1b)^T as [n][kp]; c1f[l][n] = b2@U1b ----
__global__ __launch_bounds__(256) void prep_k(
    const unsigned short* __restrict__ wt, const float* __restrict__ mlp_b2,
    unsigned short* __restrict__ wt2, float* __restrict__ c1f)
{
    __shared__ unsigned short Bs[128][136];
    int l = blockIdx.x;
    const unsigned short* u1bt = wt + l*WPL + 49152 + 128;  // A: [n][m], row stride 256
    const unsigned short* w2t  = wt + l*WPL + 32768;        // [m][kp], row stride 128
    int tid = threadIdx.x, wave = tid >> 6, lane = tid & 63;
    int cl = lane & 15, quad = lane >> 4;
    int grow0 = wave * 32;
    floatx4 zero = {0.f,0.f,0.f,0.f};
    floatx4 acc0[8], acc1[8];
    short8 a0[4], a1[4];
    #pragma unroll
    for (int k = 0; k < 4; ++k) {
        a0[k] = *(const short8*)(u1bt + (long)(grow0 + cl)*256 + k*32 + quad*8);
        a1[k] = *(const short8*)(u1bt + (long)(grow0 + 16 + cl)*256 + k*32 + quad*8);
    }
    for (int i = 0; i < 64; ++i) {
        int idx = i*256 + tid;
        int m = idx >> 7, kp = idx & 127;
        Bs[kp][m] = w2t[m*128 + kp];
    }
    __syncthreads();
    #pragma unroll
    for (int t = 0; t < 8; ++t) { acc0[t] = zero; acc1[t] = zero; }
    #pragma unroll
    for (int k = 0; k < 4; ++k) {
        #pragma unroll
        for (int t = 0; t < 8; ++t) {
            short8 bf = *(const short8*)(&Bs[t*16 + cl][k*32 + quad*8]);
            acc0[t] = __builtin_amdgcn_mfma_f32_16x16x32_bf16(a0[k], bf, acc0[t], 0, 0, 0);
            acc1[t] = __builtin_amdgcn_mfma_f32_16x16x32_bf16(a1[k], bf, acc1[t], 0, 0, 0);
        }
    }
    #pragma unroll
    for (int t = 0; t < 8; ++t) {
        int col = t*16 + cl;
        #pragma unroll
        for (int r = 0; r < 4; ++r) {
            int n0 = grow0 + quad*4 + r, n1 = grow0 + 16 + quad*4 + r;
            wt2[(long)l*16384 + n0*128 + col] = f2bf(acc0[t][r]);
            wt2[(long)l*16384 + n1*128 + col] = f2bf(acc1[t][r]);
        }
    }
    if (tid < 128) {
        const float* mb2 = mlp_b2 + l*128;
        float acc = 0.f;
        for (int m = 0; m < 128; ++m)
            acc += mb2[m] * bf2f(u1bt[(long)tid*256 + m]);
        c1f[l*128 + tid] = acc;
    }
}

// ---- CSR build: hist also records each edge's rank within its dst bucket ----
__global__ __launch_bounds__(256) void hist_k(const int* __restrict__ dst,
                                              int* __restrict__ cnt, int* __restrict__ rank) {
    int e = blockIdx.x * 256 + threadIdx.x;
    rank[e] = atomicAdd(&cnt[dst[e]], 1);
}

__global__ __launch_bounds__(256) void scan1_k(const int* __restrict__ cnt,
                                               int* __restrict__ offs, int* __restrict__ btot)
{
    __shared__ int wsum[4];
    int tid = threadIdx.x, lane = tid & 63, wave = tid >> 6;
    int gid = blockIdx.x * 256 + tid;
    int4 v = ((const int4*)cnt)[gid];
    int tot = v.x + v.y + v.z + v.w;
    int sc = tot;
    #pragma unroll
    for (int o = 1; o < 64; o <<= 1) {
        int t = __shfl_up(sc, o);
        if (lane >= o) sc += t;
    }
    if (lane == 63) wsum[wave] = sc;
    __syncthreads();
    int woff = 0;
    #pragma unroll
    for (int i = 0; i < 3; ++i) if (i < wave) woff += wsum[i];
    int excl = woff + sc - tot;
    int4 o;
    o.x = excl; o.y = excl + v.x; o.z = o.y + v.y; o.w = o.z + v.z;
    ((int4*)offs)[gid] = o;
    if (tid == 255) btot[blockIdx.x] = woff + sc;
}

// merged scan2+3: each block reduces btot[0..blockIdx) itself, adds to its offs chunk
__global__ __launch_bounds__(256) void scan23_k(const int* __restrict__ btot, int* __restrict__ offs)
{
    __shared__ int psh;
    int tid = threadIdx.x;
    if (tid < 64) {
        int v = (tid < blockIdx.x) ? btot[tid] : 0;   // blockIdx < 49
        #pragma unroll
        for (int o = 32; o > 0; o >>= 1) v += __shfl_down(v, o);
        if (tid == 0) psh = v;
    }
    __syncthreads();
    int gid = blockIdx.x * 256 + tid;
    int p = psh;
    int4 o = ((int4*)offs)[gid];
    o.x += p; o.y += p; o.z += p; o.w += p;
    ((int4*)offs)[gid] = o;
}

// ---- single-pass coalesced placement: pos = offs[dst[e]] + rank[e] (no atomics) ----
__global__ __launch_bounds__(256) void place_k(
    const int* __restrict__ src, const int* __restrict__ dst,
    const float* __restrict__ ea, const int* __restrict__ offs,
    const int* __restrict__ rank, unsigned int* __restrict__ sorted)
{
    int e = blockIdx.x * 256 + threadIdx.x;
    int d = dst[e];
    int pos = offs[d] + rank[e];
    unsigned pr = ((unsigned)f2bf(ea[e]) << 16) | (unsigned)src[e];
    sorted[pos] = pr;
}

// ---- per-node aggregation, 8 independent gather chains in flight ----
__global__ __launch_bounds__(512) void aggregate_k(
    const unsigned short* __restrict__ PQ,
    const unsigned int* __restrict__ sorted, const int* __restrict__ offs,
    const int* __restrict__ cnt,
    const float* __restrict__ w1c, unsigned short* __restrict__ Hb)
{
    int wave = threadIdx.x >> 6, lane = threadIdx.x & 63;
    int n = blockIdx.x * 8 + wave;      // grid 6250*8 = 50000 exactly
    int i0 = lane * 2;
    float2 w = *(const float2*)(w1c + i0);
    ushort2 p2 = *(const ushort2*)(PQ + (long)n*256 + i0);
    float p0 = bf2f(p2.x), p1 = bf2f(p2.y);
    int s = offs[n], c = cnt[n];
    const unsigned short* Qb = PQ + 128 + i0;
    float a00 = 0.f, a01 = 0.f, a10 = 0.f, a11 = 0.f;
    float a20 = 0.f, a21 = 0.f, a30 = 0.f, a31 = 0.f;
    int j = 0;
    for (; j + 8 <= c; j += 8) {
        uint4 sa = *(const uint4*)(sorted + s + j);
        uint4 sb = *(const uint4*)(sorted + s + j + 4);
        ushort2 q0 = *(const ushort2*)(Qb + (long)(sa.x & 0xffffu)*256);
        ushort2 q1 = *(const ushort2*)(Qb + (long)(sa.y & 0xffffu)*256);
        ushort2 q2 = *(const ushort2*)(Qb + (long)(sa.z & 0xffffu)*256);
        ushort2 q3 = *(const ushort2*)(Qb + (long)(sa.w & 0xffffu)*256);
        ushort2 q4 = *(const ushort2*)(Qb + (long)(sb.x & 0xffffu)*256);
        ushort2 q5 = *(const ushort2*)(Qb + (long)(sb.y & 0xffffu)*256);
        ushort2 q6 = *(const ushort2*)(Qb + (long)(sb.z & 0xffffu)*256);
        ushort2 q7 = *(const ushort2*)(Qb + (long)(sb.w & 0xffffu)*256);
        float v0 = bf2f((unsigned short)(sa.x >> 16)), v1 = bf2f((unsigned short)(sa.y >> 16));
        float v2 = bf2f((unsigned short)(sa.z >> 16)), v3 = bf2f((unsigned short)(sa.w >> 16));
        float v4 = bf2f((unsigned short)(sb.x >> 16)), v5 = bf2f((unsigned short)(sb.y >> 16));
        float v6 = bf2f((unsigned short)(sb.z >> 16)), v7 = bf2f((unsigned short)(sb.w >> 16));
        a00 += fmaxf(p0 + bf2f(q0.x) + v0*w.x, 0.f);
        a01 += fmaxf(p1 + bf2f(q0.y) + v0*w.y, 0.f);
        a10 += fmaxf(p0 + bf2f(q1.x) + v1*w.x, 0.f);
        a11 += fmaxf(p1 + bf2f(q1.y) + v1*w.y, 0.f);
        a20 += fmaxf(p0 + bf2f(q2.x) + v2*w.x, 0.f);
        a21 += fmaxf(p1 + bf2f(q2.y) + v2*w.y, 0.f);
        a30 += fmaxf(p0 + bf2f(q3.x) + v3*w.x, 0.f);
        a31 += fmaxf(p1 + bf2f(q3.y) + v3*w.y, 0.f);
        a00 += fmaxf(p0 + bf2f(q4.x) + v4*w.x, 0.f);
        a01 += fmaxf(p1 + bf2f(q4.y) + v4*w.y, 0.f);
        a10 += fmaxf(p0 + bf2f(q5.x) + v5*w.x, 0.f);
        a11 += fmaxf(p1 + bf2f(q5.y) + v5*w.y, 0.f);
        a20 += fmaxf(p0 + bf2f(q6.x) + v6*w.x, 0.f);
        a21 += fmaxf(p1 + bf2f(q6.y) + v6*w.y, 0.f);
        a30 += fmaxf(p0 + bf2f(q7.x) + v7*w.x, 0.f);
        a31 += fmaxf(p1 + bf2f(q7.y) + v7*w.y, 0.f);
    }
    for (; j + 4 <= c; j += 4) {
        uint4 sa = *(const uint4*)(sorted + s + j);
        ushort2 q0 = *(const ushort2*)(Qb + (long)(sa.x & 0xffffu)*256);
        ushort2 q1 = *(const ushort2*)(Qb + (long)(sa.y & 0xffffu)*256);
        ushort2 q2 = *(const ushort2*)(Qb + (long)(sa.z & 0xffffu)*256);
        ushort2 q3 = *(const ushort2*)(Qb + (long)(sa.w & 0xffffu)*256);
        float v0 = bf2f((unsigned short)(sa.x >> 16)), v1 = bf2f((unsigned short)(sa.y >> 16));
        float v2 = bf2f((unsigned short)(sa.z >> 16)), v3 = bf2f((unsigned short)(sa.w >> 16));
        a00 += fmaxf(p0 + bf2f(q0.x) + v0*w.x, 0.f);
        a01 += fmaxf(p1 + bf2f(q0.y) + v0*w.y, 0.f);
        a10 += fmaxf(p0 + bf2f(q1.x) + v1*w.x, 0.f);
        a11 += fmaxf(p1 + bf2f(q1.y) + v1*w.y, 0.f);
        a20 += fmaxf(p0 + bf2f(q2.x) + v2*w.x, 0.f);
        a21 += fmaxf(p1 + bf2f(q2.y) + v2*w.y, 0.f);
        a30 += fmaxf(p0 + bf2f(q3.x) + v3*w.x, 0.f);
        a31 += fmaxf(p1 + bf2f(q3.y) + v3*w.y, 0.f);
    }
    for (; j < c; ++j) {
        unsigned e0 = sorted[s+j];
        ushort2 q0 = *(const ushort2*)(Qb + (long)(e0 & 0xffffu)*256);
        float v0 = bf2f((unsigned short)(e0 >> 16));
        a00 += fmaxf(p0 + bf2f(q0.x) + v0*w.x, 0.f);
        a01 += fmaxf(p1 + bf2f(q0.y) + v0*w.y, 0.f);
    }
    float a0 = (a00 + a10) + (a20 + a30);
    float a1 = (a01 + a11) + (a21 + a31);
    float inv = 1.0f / fmaxf((float)c, 1.0f);
    ushort2 o; o.x = f2bf(a0 * inv); o.y = f2bf(a1 * inv);
    *(ushort2*)(Hb + (long)n*128 + i0) = o;
}

// ======== macros ========
// enc_pq: 128-row/256-thread, K=64 staging
#define STAGE_B64(ptr, stride, k0) { __syncthreads(); _Pragma("unroll") \
    for (int it = 0; it < 8; ++it) { int idx = it*1024 + tid*4; int r = idx >> 6, c = idx & 63; \
        *(ushort4*)(&Bs[r][c]) = *(const ushort4*)((ptr) + (long)r*(stride) + (k0) + c); } \
    __syncthreads(); }
#define MFMA_L64(k0) { _Pragma("unroll") for (int kk = 0; kk < 64; kk += 32) { \
    short8 a0 = *(const short8*)(&buf[wrow + cl][(k0) + kk + quad*8]); \
    short8 a1 = *(const short8*)(&buf[wrow + 16 + cl][(k0) + kk + quad*8]); \
    _Pragma("unroll") for (int t = 0; t < 8; ++t) { \
        short8 bf = *(const short8*)(&Bs[t*16 + cl][kk + quad*8]); \
        acc0[t] = __builtin_amdgcn_mfma_f32_16x16x32_bf16(a0, bf, acc0[t], 0, 0, 0); \
        acc1[t] = __builtin_amdgcn_mfma_f32_16x16x32_bf16(a1, bf, acc1[t], 0, 0, 0); } } }
// fused_update: 64-row/128-thread, full-K=128 staging (32 ushort4/thread)
#define STAGE_BF128(ptr, stride) { __syncthreads(); _Pragma("unroll") \
    for (int it = 0; it < 32; ++it) { int q = it*128 + tid; int r = q >> 5, c = (q & 31)*4; \
        *(ushort4*)(&Bs[r][c]) = *(const ushort4*)((ptr) + (long)r*(stride) + c); } \
    __syncthreads(); }
#define MFMA_L4() { _Pragma("unroll") for (int kk = 0; kk < 128; kk += 32) { \
    short8 a0 = *(const short8*)(&buf[wrow + cl][kk + quad*8]); \
    short8 a1 = *(const short8*)(&buf[wrow + 16 + cl][kk + quad*8]); \
    _Pragma("unroll") for (int t = 0; t < 8; ++t) { \
        short8 bf = *(const short8*)(&Bs[t*16 + cl][kk + quad*8]); \
        acc0[t] = __builtin_amdgcn_mfma_f32_16x16x32_bf16(a0, bf, acc0[t], 0, 0, 0); \
        acc1[t] = __builtin_amdgcn_mfma_f32_16x16x32_bf16(a1, bf, acc1[t], 0, 0, 0); } } }
#define PRELOAD_A128(d0, d1, aptr, astride) { _Pragma("unroll") \
    for (int k = 0; k < 4; ++k) { \
        d0[k] = *(const short8*)((aptr) + (long)(grow0 + cl)*(astride) + k*32 + quad*8); \
        d1[k] = *(const short8*)((aptr) + (long)(grow0 + 16 + cl)*(astride) + k*32 + quad*8); } }
#define MFMA_R4(p0, p1) { _Pragma("unroll") for (int k = 0; k < 4; ++k) { \
    _Pragma("unroll") for (int t = 0; t < 8; ++t) { \
        short8 bf = *(const short8*)(&Bs[t*16 + cl][k*32 + quad*8]); \
        acc0[t] = __builtin_amdgcn_mfma_f32_16x16x32_bf16(p0[k], bf, acc0[t], 0, 0, 0); \
        acc1[t] = __builtin_amdgcn_mfma_f32_16x16x32_bf16(p1[k], bf, acc1[t], 0, 0, 0); } } }
#define ZACC() { _Pragma("unroll") for (int t = 0; t < 8; ++t) { acc0[t] = zero; acc1[t] = zero; } }

// ---- fused encoder + PQ0 (128 rows, 256 threads, K=64 staging, 3 blocks/CU) ----
__global__ __launch_bounds__(256, 3) void enc_pq_k(
    const float* __restrict__ nf, const float* __restrict__ encW, const float* __restrict__ encb,
    const unsigned short* __restrict__ w1abt,   // [256][128] layer-0
    const float* __restrict__ mb1,
    unsigned short* __restrict__ u_in, unsigned short* __restrict__ PQ)
{
    __shared__ unsigned short Bs[128][72];
    __shared__ unsigned short buf[128][136];
    int tid = threadIdx.x, wave = tid >> 6, lane = tid & 63;
    int cl = lane & 15, quad = lane >> 4;
    int row0 = blockIdx.x * 128;
    int wrow = wave * 32;
    int grow0 = row0 + wrow;
    floatx4 zero = {0.f,0.f,0.f,0.f};
    floatx4 acc0[8], acc1[8];

    float* nfs = (float*)&Bs[0][0];             // 640 floats = 2.5 KB
    for (int i = tid; i < 640; i += 256) {
        int gi = row0*5 + i;
        nfs[i] = (gi < NNODES*5) ? nf[gi] : 0.f;
    }
    __syncthreads();
    {
        int c = tid & 127, h = tid >> 7;
        float w0 = encW[c], w1 = encW[128 + c], w2 = encW[256 + c], w3 = encW[384 + c], w4 = encW[512 + c];
        float bb = encb[c];
        for (int rr = 0; rr < 64; ++rr) {
            int r = h*64 + rr;
            float a = bb + nfs[r*5]*w0 + nfs[r*5+1]*w1 + nfs[r*5+2]*w2
                         + nfs[r*5+3]*w3 + nfs[r*5+4]*w4;
            unsigned short hv = f2bf(a);
            buf[r][c] = hv;
            int grow = row0 + r;
            if (grow < NNODES) u_in[(long)grow*256 + c] = hv;
        }
    }
    #pragma unroll
    for (int half = 0; half < 2; ++half) {
        ZACC();
        STAGE_B64(w1abt + half*16384, 128, 0);   MFMA_L64(0);
        STAGE_B64(w1abt + half*16384, 128, 64);  MFMA_L64(64);
        #pragma unroll
        for (int t = 0; t < 8; ++t) {
            int col = t*16 + cl;
            float bv = (half == 0) ? mb1[col] : 0.f;
            #pragma unroll
            for (int r = 0; r < 4; ++r) {
                int g0 = grow0 + quad*4 + r, g1 = grow0 + 16 + quad*4 + r;
                PQ[(long)g0*256 + half*128 + col] = f2bf(acc0[t][r] + bv);
                PQ[(long)g1*256 + half*128 + col] = f2bf(acc1[t][r] + bv);
            }
        }
    }
}

// ---- fused per-layer update: 64-row blocks, 128 threads (2 waves), M=32/wave,
//      folded stage-1, full-K staging, 5 segments. 782 blocks ≈ 3/CU (balanced tail). ----
__global__ __launch_bounds__(128, 2) void fused_update_k(
    const unsigned short* __restrict__ Hb,      // [50048][128]
    const unsigned short* __restrict__ u1t,     // [128][256] (U1^T; k cols 0..128 = U1a)
    const unsigned short* __restrict__ wt2l,    // [128][128] (W2@U1b)^T
    const unsigned short* __restrict__ u2t,     // [128][128]
    const unsigned short* __restrict__ w1abt,   // [256][128] next-layer, or null
    const float* __restrict__ c1l,              // [128] b2@U1b
    const int* __restrict__ cnt,
    const float* __restrict__ ub1, const float* __restrict__ ub2,
    const float* __restrict__ lng, const float* __restrict__ lnb,
    const float* __restrict__ mb1n,             // next-layer b1, or null
    unsigned short* __restrict__ u_in,          // x at stride 256 (read cols 0:128, write x')
    unsigned short* __restrict__ PQ,            // [50048][256] out (if w1abt)
    float* __restrict__ sumv)                   // [128] colsum out (if !w1abt)
{
    __shared__ unsigned short Bs[128][136];     // staged B (N=128 x K=128, +pad) 34.8 KB
    __shared__ unsigned short buf[64][136];     // inter-stage A (wave-row-partitioned) 17.4 KB
    int tid = threadIdx.x, wave = tid >> 6, lane = tid & 63;
    int cl = lane & 15, quad = lane >> 4;
    int row0 = blockIdx.x * 64;
    int wrow = wave * 32;
    int grow0 = row0 + wrow;
    floatx4 zero = {0.f,0.f,0.f,0.f};
    floatx4 acc0[8], acc1[8];

    short8 hA0[4], hA1[4], xA0[4], xA1[4];
    PRELOAD_A128(hA0, hA1, Hb, 128);
    PRELOAD_A128(xA0, xA1, u_in, 256);

    // ---------- stage A: u_hid = relu(x@U1a + Hb@W2U1b + mask*c1 + ub1) -> buf ----------
    ZACC();
    STAGE_BF128(u1t, 256);   MFMA_R4(xA0, xA1);
    STAGE_BF128(wt2l, 128);  MFMA_R4(hA0, hA1);
    {
        float mask0[4], mask1[4];
        #pragma unroll
        for (int r = 0; r < 4; ++r) {
            mask0[r] = (cnt[grow0 + quad*4 + r] > 0) ? 1.f : 0.f;
            mask1[r] = (cnt[grow0 + 16 + quad*4 + r] > 0) ? 1.f : 0.f;
        }
        #pragma unroll
        for (int t = 0; t < 8; ++t) {
            int col = t*16 + cl;
            float bv = ub1[col], cv = c1l[col];
            #pragma unroll
            for (int r = 0; r < 4; ++r) {
                buf[wrow + quad*4 + r][col]      = f2bf(fmaxf(acc0[t][r] + mask0[r]*cv + bv, 0.f));
                buf[wrow + 16 + quad*4 + r][col] = f2bf(fmaxf(acc1[t][r] + mask1[r]*cv + bv, 0.f));
            }
        }
    }

    // ---------- stage B: y = u_hid@U2 + ub2 ; x' = relu(LN(y)*g+b) -> global + buf ----------
    ZACC();
    STAGE_BF128(u2t, 128);   MFMA_L4();
    float colacc[8];
    {
        float rs0[4] = {0,0,0,0}, rq0[4] = {0,0,0,0}, rs1[4] = {0,0,0,0}, rq1[4] = {0,0,0,0};
        #pragma unroll
        for (int t = 0; t < 8; ++t) {
            float bv = ub2[t*16 + cl];
            #pragma unroll
            for (int r = 0; r < 4; ++r) {
                acc0[t][r] += bv; rs0[r] += acc0[t][r]; rq0[r] += acc0[t][r]*acc0[t][r];
                acc1[t][r] += bv; rs1[r] += acc1[t][r]; rq1[r] += acc1[t][r]*acc1[t][r];
            }
        }
        #pragma unroll
        for (int o = 1; o < 16; o <<= 1) {
            #pragma unroll
            for (int r = 0; r < 4; ++r) {
                rs0[r] += __shfl_xor(rs0[r], o); rq0[r] += __shfl_xor(rq0[r], o);
                rs1[r] += __shfl_xor(rs1[r], o); rq1[r] += __shfl_xor(rq1[r], o);
            }
        }
        float mu0[4], iv0[4], mu1[4], iv1[4];
        #pragma unroll
        for (int r = 0; r < 4; ++r) {
            mu0[r] = rs0[r] * (1.f/128.f);
            iv0[r] = rsqrtf(rq0[r] * (1.f/128.f) - mu0[r]*mu0[r] + 1e-5f);
            mu1[r] = rs1[r] * (1.f/128.f);
            iv1[r] = rsqrtf(rq1[r] * (1.f/128.f) - mu1[r]*mu1[r] + 1e-5f);
        }
        #pragma unroll
        for (int t = 0; t < 8; ++t) {
            int col = t*16 + cl;
            float gv = lng[col], bb = lnb[col];
            float s = 0.f;
            #pragma unroll
            for (int r = 0; r < 4; ++r) {
                float y0 = fmaxf((acc0[t][r] - mu0[r]) * iv0[r] * gv + bb, 0.f);
                float y1 = fmaxf((acc1[t][r] - mu1[r]) * iv1[r] * gv + bb, 0.f);
                unsigned short h0 = f2bf(y0), h1 = f2bf(y1);
                int g0 = grow0 + quad*4 + r, g1 = grow0 + 16 + quad*4 + r;
                if (g0 < NNODES) { u_in[(long)g0*256 + col] = h0; s += y0; }
                if (g1 < NNODES) { u_in[(long)g1*256 + col] = h1; s += y1; }
                buf[wrow + quad*4 + r][col]      = h0;
                buf[wrow + 16 + quad*4 + r][col] = h1;
            }
            colacc[t] = s;
        }
    }

    if (w1abt) {
        // ---------- stage C: PQ' = x'@W1ab' (+b1' on P half) ----------
        #pragma unroll
        for (int half = 0; half < 2; ++half) {
            ZACC();
            STAGE_BF128(w1abt + half*16384, 128);
            MFMA_L4();
            #pragma unroll
            for (int t = 0; t < 8; ++t) {
                int col = t*16 + cl;
                float bv = (half == 0) ? mb1n[col] : 0.f;
                #pragma unroll
                for (int r = 0; r < 4; ++r) {
                    int g0 = grow0 + quad*4 + r, g1 = grow0 + 16 + quad*4 + r;
                    PQ[(long)g0*256 + half*128 + col] = f2bf(acc0[t][r] + bv);
                    PQ[(long)g1*256 + half*128 + col] = f2bf(acc1[t][r] + bv);
                }
            }
        }
    } else {
        // ---------- last layer: block-reduce column sums of x' into sumv ----------
        #pragma unroll
        for (int t = 0; t < 8; ++t) {
            colacc[t] += __shfl_xor(colacc[t], 16);
            colacc[t] += __shfl_xor(colacc[t], 32);
        }
        float* red = (float*)&buf[0][0];   // 256 floats, buf no longer needed
        __syncthreads();
        if (lane < 16) {
            #pragma unroll
            for (int t = 0; t < 8; ++t) red[wave*128 + t*16 + lane] = colacc[t];
        }
        __syncthreads();
        if (tid < 128) {
            float s = red[tid] + red[128 + tid];
            atomicAdd(&sumv[tid], s);
        }
    }
}

// ---- final tiny MLP on the mean (fp32) ----
__global__ __launch_bounds__(128) void final_k(
    const float* __restrict__ sum, const float* __restrict__ W1, const float* __restrict__ b1,
    const float* __restrict__ W2, const float* __restrict__ b2, float* __restrict__ out)
{
    __shared__ float gbuf[128], hbuf[128];
    int t = threadIdx.x;
    gbuf[t] = sum[t] * (1.f / 50000.f);
    __syncthreads();
    float a = b1[t];
    for (int k = 0; k < 128; ++k) a += gbuf[k] * W1[k*128 + t];
    hbuf[t] = fmaxf(a, 0.f);
    __syncthreads();
    float o = b2[t];
    for (int k = 0; k < 128; ++k) o += hbuf[k] * W2[k*128 + t];
    out[t] = o;
}

extern "C" void kernel_launch(void* const* d_in, const int* in_sizes, int n_in,
                              void* d_out, int out_size, void* d_ws, size_t ws_size,
                              hipStream_t stream)
{
    const float* node_feat = (const float*)d_in[0];
    const float* edge_attr = (const float*)d_in[1];
    const float* enc_W  = (const float*)d_in[2];
    const float* enc_b  = (const float*)d_in[3];
    const float* mlp_W1 = (const float*)d_in[4];
    const float* mlp_b1 = (const float*)d_in[5];
    const float* mlp_W2 = (const float*)d_in[6];
    const float* mlp_b2 = (const float*)d_in[7];
    const float* upd_W1 = (const float*)d_in[8];
    const float* upd_b1 = (const float*)d_in[9];
    const float* upd_W2 = (const float*)d_in[10];
    const float* upd_b2 = (const float*)d_in[11];
    const float* ln_g   = (const float*)d_in[12];
    const float* ln_b   = (const float*)d_in[13];
    const float* out_W1 = (const float*)d_in[14];
    const float* out_b1 = (const float*)d_in[15];
    const float* out_W2 = (const float*)d_in[16];
    const float* out_b2 = (const float*)d_in[17];
    const int* edge_index = (const int*)d_in[18];
    const int* e_src = edge_index;
    const int* e_dst = edge_index + NEDGES;

    // workspace layout (padded node rows = 50048; scan arrays padded to 50176)
    char* ws = (char*)d_ws;
    unsigned short* u_in = (unsigned short*)(ws + 0);          // [50048][256] bf16: [x | scratch]
    unsigned short* PQ   = (unsigned short*)(ws + 25624576);   // [50048][256] bf16: [P | Q]
    unsigned short* Hb   = (unsigned short*)(ws + 51249152);   // [50048][128] bf16
    unsigned int* sorted = (unsigned int*)(ws + 64061440);     // [800000] packed {bf16 ea | u16 src}
    float* sumv          = (float*)(ws + 70460928);            // [128] (adjacent to cnt: one memset)
    int* cnt             = (int*)(ws + 70461440);              // [50176]
    int* offs            = (int*)(ws + 70662144);              // [50176]
    int* btot            = (int*)(ws + 70862848);              // [64]
    unsigned short* wt   = (unsigned short*)(ws + 70863360);   // [3*WPL] bf16 weights
    unsigned short* wt2  = (unsigned short*)(ws + 71453184);   // [3*16384] bf16 (W2@U1b)^T
    float* c1f           = (float*)(ws + 71551488);            // [3*128] b2@U1b
    int* rank            = (int*)(ws + 71553024);              // [800000] edge rank in dst bucket

    hipMemsetAsync(sumv, 0, 512 + NPAD*4, stream);   // zeroes sumv + cnt in one launch
    cvt_weights<<<1152, 256, 0, stream>>>(mlp_W1, mlp_W2, upd_W1, upd_W2, wt);
    prep_k<<<3, 256, 0, stream>>>(wt, mlp_b2, wt2, c1f);
    hist_k<<<3125, 256, 0, stream>>>(e_dst, cnt, rank);
    scan1_k<<<49, 256, 0, stream>>>(cnt, offs, btot);
    scan23_k<<<49, 256, 0, stream>>>(btot, offs);
    place_k<<<3125, 256, 0, stream>>>(e_src, e_dst, edge_attr, offs, rank, sorted);

    // fused encoder + PQ0 (layer-0 weights)
    enc_pq_k<<<391, 256, 0, stream>>>(node_feat, enc_W, enc_b, wt, mlp_b1, u_in, PQ);

    for (int l = 0; l < 3; ++l) {
        const unsigned short* u1t = wt + l*WPL + 49152;    // [128][256]
        const unsigned short* u2t = wt + l*WPL + 81920;    // [128][128]
        // Hb = inv_deg * segsum(relu(P[dst]+Q[src]+ea*w1c))
        aggregate_k<<<6250, 512, 0, stream>>>(PQ, sorted, offs, cnt,
                                              mlp_W1 + (l*257 + 256)*128, Hb);
        // fused: u_hid (folded aggr) -> x' (LN) -> PQ for layer l+1 (or colsum on last layer)
        fused_update_k<<<782, 128, 0, stream>>>(
            Hb, u1t, wt2 + (long)l*16384, u2t,
            (l < 2) ? (wt + (l+1)*WPL) : nullptr,
            c1f + l*128, cnt,
            upd_b1 + l*128, upd_b2 + l*128,
            ln_g + l*128, ln_b + l*128,
            (l < 2) ? (mlp_b1 + (l+1)*128) : nullptr,
            u_in, PQ, sumv);
    }
    final_k<<<1, 128, 0, stream>>>(sumv, out_W1, out_b1, out_W2, out_b2, (float*)d_out);
}

// Round 18
// 379.622 us; speedup vs baseline: 1.2091x; 1.2091x over previous
//
#include <hip/hip_runtime.h>
#include <stdint.h>

#define HID 128
#define NNODES 50000
#define NEDGES 800000
#define WPL 98304   // bf16 weight elems per layer in wt scratch
#define NPAD 50176  // padded node count (= 196*256 = 49*1024)

typedef __attribute__((ext_vector_type(8))) short short8;
typedef __attribute__((ext_vector_type(4))) float floatx4;

__device__ __forceinline__ float bf2f(unsigned short h) {
    union { unsigned int u; float f; } v; v.u = ((unsigned int)h) << 16; return v.f;
}
__device__ __forceinline__ unsigned short f2bf(float f) {
    union { float f; unsigned int u; } v; v.f = f;
    unsigned int u = v.u;
    return (unsigned short)((u + 0x7fffu + ((u >> 16) & 1u)) >> 16);
}

// ---- convert all layer weights to bf16, transposed to [n][k] for MFMA B-frags ----
// layout per layer l: [W1a^T 128x128 | W1b^T 128x128 | W2^T 128x128 | U1^T 128x256 | U2^T 128x128]
__global__ __launch_bounds__(256) void cvt_weights(
    const float* __restrict__ mW1, const float* __restrict__ mW2,
    const float* __restrict__ uW1, const float* __restrict__ uW2,
    unsigned short* __restrict__ wt)
{
    int id = blockIdx.x * 256 + threadIdx.x;
    int l = id / WPL;
    int r = id - l * WPL;
    float v;
    if (r < 16384)      { int n = r >> 7, k = r & 127;                v = mW1[(l*257 + k)*128 + n]; }
    else if (r < 32768) { int q = r - 16384; int n = q >> 7, k = q & 127; v = mW1[(l*257 + 128 + k)*128 + n]; }
    else if (r < 49152) { int q = r - 32768; int n = q >> 7, k = q & 127; v = mW2[(l*128 + k)*128 + n]; }
    else if (r < 81920) { int q = r - 49152; int n = q >> 8, k = q & 255; v = uW1[(l*256 + k)*128 + n]; }
    else                { int q = r - 81920; int n = q >> 7, k = q & 127; v = uW2[(l*128 + k)*128 + n]; }
    wt[id] = f2bf(v);
}

// ---- prep (MFMA): wt2[l] = (W2@U1b)^T as [n][kp]; c1f[l][n] = b2@U1b ----
__global__ __launch_bounds__(256) void prep_k(
    const unsigned short* __restrict__ wt, const float* __restrict__ mlp_b2,
    unsigned short* __restrict__ wt2, float* __restrict__ c1f)
{
    __shared__ unsigned short Bs[128][136];
    int l = blockIdx.x;
    const unsigned short* u1bt = wt + l*WPL + 49152 + 128;  // A: [n][m], row stride 256
    const unsigned short* w2t  = wt + l*WPL + 32768;        // [m][kp], row stride 128
    int tid = threadIdx.x, wave = tid >> 6, lane = tid & 63;
    int cl = lane & 15, quad = lane >> 4;
    int grow0 = wave * 32;
    floatx4 zero = {0.f,0.f,0.f,0.f};
    floatx4 acc0[8], acc1[8];
    short8 a0[4], a1[4];
    #pragma unroll
    for (int k = 0; k < 4; ++k) {
        a0[k] = *(const short8*)(u1bt + (long)(grow0 + cl)*256 + k*32 + quad*8);
        a1[k] = *(const short8*)(u1bt + (long)(grow0 + 16 + cl)*256 + k*32 + quad*8);
    }
    for (int i = 0; i < 64; ++i) {
        int idx = i*256 + tid;
        int m = idx >> 7, kp = idx & 127;
        Bs[kp][m] = w2t[m*128 + kp];
    }
    __syncthreads();
    #pragma unroll
    for (int t = 0; t < 8; ++t) { acc0[t] = zero; acc1[t] = zero; }
    #pragma unroll
    for (int k = 0; k < 4; ++k) {
        #pragma unroll
        for (int t = 0; t < 8; ++t) {
            short8 bf = *(const short8*)(&Bs[t*16 + cl][k*32 + quad*8]);
            acc0[t] = __builtin_amdgcn_mfma_f32_16x16x32_bf16(a0[k], bf, acc0[t], 0, 0, 0);
            acc1[t] = __builtin_amdgcn_mfma_f32_16x16x32_bf16(a1[k], bf, acc1[t], 0, 0, 0);
        }
    }
    #pragma unroll
    for (int t = 0; t < 8; ++t) {
        int col = t*16 + cl;
        #pragma unroll
        for (int r = 0; r < 4; ++r) {
            int n0 = grow0 + quad*4 + r, n1 = grow0 + 16 + quad*4 + r;
            wt2[(long)l*16384 + n0*128 + col] = f2bf(acc0[t][r]);
            wt2[(long)l*16384 + n1*128 + col] = f2bf(acc1[t][r]);
        }
    }
    if (tid < 128) {
        const float* mb2 = mlp_b2 + l*128;
        float acc = 0.f;
        for (int m = 0; m < 128; ++m)
            acc += mb2[m] * bf2f(u1bt[(long)tid*256 + m]);
        c1f[l*128 + tid] = acc;
    }
}

// ---- CSR build: hist also records each edge's rank within its dst bucket ----
__global__ __launch_bounds__(256) void hist_k(const int* __restrict__ dst,
                                              int* __restrict__ cnt, int* __restrict__ rank) {
    int e = blockIdx.x * 256 + threadIdx.x;
    rank[e] = atomicAdd(&cnt[dst[e]], 1);
}

__global__ __launch_bounds__(256) void scan1_k(const int* __restrict__ cnt,
                                               int* __restrict__ offs, int* __restrict__ btot)
{
    __shared__ int wsum[4];
    int tid = threadIdx.x, lane = tid & 63, wave = tid >> 6;
    int gid = blockIdx.x * 256 + tid;
    int4 v = ((const int4*)cnt)[gid];
    int tot = v.x + v.y + v.z + v.w;
    int sc = tot;
    #pragma unroll
    for (int o = 1; o < 64; o <<= 1) {
        int t = __shfl_up(sc, o);
        if (lane >= o) sc += t;
    }
    if (lane == 63) wsum[wave] = sc;
    __syncthreads();
    int woff = 0;
    #pragma unroll
    for (int i = 0; i < 3; ++i) if (i < wave) woff += wsum[i];
    int excl = woff + sc - tot;
    int4 o;
    o.x = excl; o.y = excl + v.x; o.z = o.y + v.y; o.w = o.z + v.z;
    ((int4*)offs)[gid] = o;
    if (tid == 255) btot[blockIdx.x] = woff + sc;
}

// merged scan2+3: each block reduces btot[0..blockIdx) itself, adds to its offs chunk
__global__ __launch_bounds__(256) void scan23_k(const int* __restrict__ btot, int* __restrict__ offs)
{
    __shared__ int psh;
    int tid = threadIdx.x;
    if (tid < 64) {
        int v = (tid < blockIdx.x) ? btot[tid] : 0;   // blockIdx < 49
        #pragma unroll
        for (int o = 32; o > 0; o >>= 1) v += __shfl_down(v, o);
        if (tid == 0) psh = v;
    }
    __syncthreads();
    int gid = blockIdx.x * 256 + tid;
    int p = psh;
    int4 o = ((int4*)offs)[gid];
    o.x += p; o.y += p; o.z += p; o.w += p;
    ((int4*)offs)[gid] = o;
}

// ---- single-pass coalesced placement: pos = offs[dst[e]] + rank[e] (no atomics) ----
__global__ __launch_bounds__(256) void place_k(
    const int* __restrict__ src, const int* __restrict__ dst,
    const float* __restrict__ ea, const int* __restrict__ offs,
    const int* __restrict__ rank, unsigned int* __restrict__ sorted)
{
    int e = blockIdx.x * 256 + threadIdx.x;
    int d = dst[e];
    int pos = offs[d] + rank[e];
    unsigned pr = ((unsigned)f2bf(ea[e]) << 16) | (unsigned)src[e];
    sorted[pos] = pr;
}

// ---- per-node aggregation, 8 independent gather chains in flight ----
__global__ __launch_bounds__(512) void aggregate_k(
    const unsigned short* __restrict__ PQ,
    const unsigned int* __restrict__ sorted, const int* __restrict__ offs,
    const int* __restrict__ cnt,
    const float* __restrict__ w1c, unsigned short* __restrict__ Hb)
{
    int wave = threadIdx.x >> 6, lane = threadIdx.x & 63;
    int n = blockIdx.x * 8 + wave;      // grid 6250*8 = 50000 exactly
    int i0 = lane * 2;
    float2 w = *(const float2*)(w1c + i0);
    ushort2 p2 = *(const ushort2*)(PQ + (long)n*256 + i0);
    float p0 = bf2f(p2.x), p1 = bf2f(p2.y);
    int s = offs[n], c = cnt[n];
    const unsigned short* Qb = PQ + 128 + i0;
    float a00 = 0.f, a01 = 0.f, a10 = 0.f, a11 = 0.f;
    float a20 = 0.f, a21 = 0.f, a30 = 0.f, a31 = 0.f;
    int j = 0;
    for (; j + 8 <= c; j += 8) {
        uint4 sa = *(const uint4*)(sorted + s + j);
        uint4 sb = *(const uint4*)(sorted + s + j + 4);
        ushort2 q0 = *(const ushort2*)(Qb + (long)(sa.x & 0xffffu)*256);
        ushort2 q1 = *(const ushort2*)(Qb + (long)(sa.y & 0xffffu)*256);
        ushort2 q2 = *(const ushort2*)(Qb + (long)(sa.z & 0xffffu)*256);
        ushort2 q3 = *(const ushort2*)(Qb + (long)(sa.w & 0xffffu)*256);
        ushort2 q4 = *(const ushort2*)(Qb + (long)(sb.x & 0xffffu)*256);
        ushort2 q5 = *(const ushort2*)(Qb + (long)(sb.y & 0xffffu)*256);
        ushort2 q6 = *(const ushort2*)(Qb + (long)(sb.z & 0xffffu)*256);
        ushort2 q7 = *(const ushort2*)(Qb + (long)(sb.w & 0xffffu)*256);
        float v0 = bf2f((unsigned short)(sa.x >> 16)), v1 = bf2f((unsigned short)(sa.y >> 16));
        float v2 = bf2f((unsigned short)(sa.z >> 16)), v3 = bf2f((unsigned short)(sa.w >> 16));
        float v4 = bf2f((unsigned short)(sb.x >> 16)), v5 = bf2f((unsigned short)(sb.y >> 16));
        float v6 = bf2f((unsigned short)(sb.z >> 16)), v7 = bf2f((unsigned short)(sb.w >> 16));
        a00 += fmaxf(p0 + bf2f(q0.x) + v0*w.x, 0.f);
        a01 += fmaxf(p1 + bf2f(q0.y) + v0*w.y, 0.f);
        a10 += fmaxf(p0 + bf2f(q1.x) + v1*w.x, 0.f);
        a11 += fmaxf(p1 + bf2f(q1.y) + v1*w.y, 0.f);
        a20 += fmaxf(p0 + bf2f(q2.x) + v2*w.x, 0.f);
        a21 += fmaxf(p1 + bf2f(q2.y) + v2*w.y, 0.f);
        a30 += fmaxf(p0 + bf2f(q3.x) + v3*w.x, 0.f);
        a31 += fmaxf(p1 + bf2f(q3.y) + v3*w.y, 0.f);
        a00 += fmaxf(p0 + bf2f(q4.x) + v4*w.x, 0.f);
        a01 += fmaxf(p1 + bf2f(q4.y) + v4*w.y, 0.f);
        a10 += fmaxf(p0 + bf2f(q5.x) + v5*w.x, 0.f);
        a11 += fmaxf(p1 + bf2f(q5.y) + v5*w.y, 0.f);
        a20 += fmaxf(p0 + bf2f(q6.x) + v6*w.x, 0.f);
        a21 += fmaxf(p1 + bf2f(q6.y) + v6*w.y, 0.f);
        a30 += fmaxf(p0 + bf2f(q7.x) + v7*w.x, 0.f);
        a31 += fmaxf(p1 + bf2f(q7.y) + v7*w.y, 0.f);
    }
    for (; j + 4 <= c; j += 4) {
        uint4 sa = *(const uint4*)(sorted + s + j);
        ushort2 q0 = *(const ushort2*)(Qb + (long)(sa.x & 0xffffu)*256);
        ushort2 q1 = *(const ushort2*)(Qb + (long)(sa.y & 0xffffu)*256);
        ushort2 q2 = *(const ushort2*)(Qb + (long)(sa.z & 0xffffu)*256);
        ushort2 q3 = *(const ushort2*)(Qb + (long)(sa.w & 0xffffu)*256);
        float v0 = bf2f((unsigned short)(sa.x >> 16)), v1 = bf2f((unsigned short)(sa.y >> 16));
        float v2 = bf2f((unsigned short)(sa.z >> 16)), v3 = bf2f((unsigned short)(sa.w >> 16));
        a00 += fmaxf(p0 + bf2f(q0.x) + v0*w.x, 0.f);
        a01 += fmaxf(p1 + bf2f(q0.y) + v0*w.y, 0.f);
        a10 += fmaxf(p0 + bf2f(q1.x) + v1*w.x, 0.f);
        a11 += fmaxf(p1 + bf2f(q1.y) + v1*w.y, 0.f);
        a20 += fmaxf(p0 + bf2f(q2.x) + v2*w.x, 0.f);
        a21 += fmaxf(p1 + bf2f(q2.y) + v2*w.y, 0.f);
        a30 += fmaxf(p0 + bf2f(q3.x) + v3*w.x, 0.f);
        a31 += fmaxf(p1 + bf2f(q3.y) + v3*w.y, 0.f);
    }
    for (; j < c; ++j) {
        unsigned e0 = sorted[s+j];
        ushort2 q0 = *(const ushort2*)(Qb + (long)(e0 & 0xffffu)*256);
        float v0 = bf2f((unsigned short)(e0 >> 16));
        a00 += fmaxf(p0 + bf2f(q0.x) + v0*w.x, 0.f);
        a01 += fmaxf(p1 + bf2f(q0.y) + v0*w.y, 0.f);
    }
    float a0 = (a00 + a10) + (a20 + a30);
    float a1 = (a01 + a11) + (a21 + a31);
    float inv = 1.0f / fmaxf((float)c, 1.0f);
    ushort2 o; o.x = f2bf(a0 * inv); o.y = f2bf(a1 * inv);
    *(ushort2*)(Hb + (long)n*128 + i0) = o;
}

// ======== macros: 128-row blocks, M=32/wave ========
#define STAGE_B64(ptr, stride, k0) { __syncthreads(); _Pragma("unroll") \
    for (int it = 0; it < 8; ++it) { int idx = it*1024 + tid*4; int r = idx >> 6, c = idx & 63; \
        *(ushort4*)(&Bs[r][c]) = *(const ushort4*)((ptr) + (long)r*(stride) + (k0) + c); } \
    __syncthreads(); }
#define MFMA_L64(k0) { _Pragma("unroll") for (int kk = 0; kk < 64; kk += 32) { \
    short8 a0 = *(const short8*)(&buf[wrow + cl][(k0) + kk + quad*8]); \
    short8 a1 = *(const short8*)(&buf[wrow + 16 + cl][(k0) + kk + quad*8]); \
    _Pragma("unroll") for (int t = 0; t < 8; ++t) { \
        short8 bf = *(const short8*)(&Bs[t*16 + cl][kk + quad*8]); \
        acc0[t] = __builtin_amdgcn_mfma_f32_16x16x32_bf16(a0, bf, acc0[t], 0, 0, 0); \
        acc1[t] = __builtin_amdgcn_mfma_f32_16x16x32_bf16(a1, bf, acc1[t], 0, 0, 0); } } }
#define STAGE_BF(ptr, stride) { __syncthreads(); _Pragma("unroll") \
    for (int it = 0; it < 16; ++it) { int q = it*256 + tid; int r = q >> 5, c = (q & 31)*4; \
        *(ushort4*)(&Bs[r][c]) = *(const ushort4*)((ptr) + (long)r*(stride) + c); } \
    __syncthreads(); }
#define MFMA_L4() { _Pragma("unroll") for (int kk = 0; kk < 128; kk += 32) { \
    short8 a0 = *(const short8*)(&buf[wrow + cl][kk + quad*8]); \
    short8 a1 = *(const short8*)(&buf[wrow + 16 + cl][kk + quad*8]); \
    _Pragma("unroll") for (int t = 0; t < 8; ++t) { \
        short8 bf = *(const short8*)(&Bs[t*16 + cl][kk + quad*8]); \
        acc0[t] = __builtin_amdgcn_mfma_f32_16x16x32_bf16(a0, bf, acc0[t], 0, 0, 0); \
        acc1[t] = __builtin_amdgcn_mfma_f32_16x16x32_bf16(a1, bf, acc1[t], 0, 0, 0); } } }
#define PRELOAD_A128(d0, d1, aptr, astride) { _Pragma("unroll") \
    for (int k = 0; k < 4; ++k) { \
        d0[k] = *(const short8*)((aptr) + (long)(grow0 + cl)*(astride) + k*32 + quad*8); \
        d1[k] = *(const short8*)((aptr) + (long)(grow0 + 16 + cl)*(astride) + k*32 + quad*8); } }
#define MFMA_R4(p0, p1) { _Pragma("unroll") for (int k = 0; k < 4; ++k) { \
    _Pragma("unroll") for (int t = 0; t < 8; ++t) { \
        short8 bf = *(const short8*)(&Bs[t*16 + cl][k*32 + quad*8]); \
        acc0[t] = __builtin_amdgcn_mfma_f32_16x16x32_bf16(p0[k], bf, acc0[t], 0, 0, 0); \
        acc1[t] = __builtin_amdgcn_mfma_f32_16x16x32_bf16(p1[k], bf, acc1[t], 0, 0, 0); } } }
#define ZACC() { _Pragma("unroll") for (int t = 0; t < 8; ++t) { acc0[t] = zero; acc1[t] = zero; } }

// ---- fused encoder + PQ0 (K=64 staging, 3 blocks/CU) ----
__global__ __launch_bounds__(256, 3) void enc_pq_k(
    const float* __restrict__ nf, const float* __restrict__ encW, const float* __restrict__ encb,
    const unsigned short* __restrict__ w1abt,   // [256][128] layer-0
    const float* __restrict__ mb1,
    unsigned short* __restrict__ u_in, unsigned short* __restrict__ PQ)
{
    __shared__ unsigned short Bs[128][72];
    __shared__ unsigned short buf[128][136];
    int tid = threadIdx.x, wave = tid >> 6, lane = tid & 63;
    int cl = lane & 15, quad = lane >> 4;
    int row0 = blockIdx.x * 128;
    int wrow = wave * 32;
    int grow0 = row0 + wrow;
    floatx4 zero = {0.f,0.f,0.f,0.f};
    floatx4 acc0[8], acc1[8];

    float* nfs = (float*)&Bs[0][0];             // 640 floats = 2.5 KB
    for (int i = tid; i < 640; i += 256) {
        int gi = row0*5 + i;
        nfs[i] = (gi < NNODES*5) ? nf[gi] : 0.f;
    }
    __syncthreads();
    {
        int c = tid & 127, h = tid >> 7;
        float w0 = encW[c], w1 = encW[128 + c], w2 = encW[256 + c], w3 = encW[384 + c], w4 = encW[512 + c];
        float bb = encb[c];
        for (int rr = 0; rr < 64; ++rr) {
            int r = h*64 + rr;
            float a = bb + nfs[r*5]*w0 + nfs[r*5+1]*w1 + nfs[r*5+2]*w2
                         + nfs[r*5+3]*w3 + nfs[r*5+4]*w4;
            unsigned short hv = f2bf(a);
            buf[r][c] = hv;
            int grow = row0 + r;
            if (grow < NNODES) u_in[(long)grow*256 + c] = hv;
        }
    }
    #pragma unroll
    for (int half = 0; half < 2; ++half) {
        ZACC();
        STAGE_B64(w1abt + half*16384, 128, 0);   MFMA_L64(0);
        STAGE_B64(w1abt + half*16384, 128, 64);  MFMA_L64(64);
        #pragma unroll
        for (int t = 0; t < 8; ++t) {
            int col = t*16 + cl;
            float bv = (half == 0) ? mb1[col] : 0.f;
            #pragma unroll
            for (int r = 0; r < 4; ++r) {
                int g0 = grow0 + quad*4 + r, g1 = grow0 + 16 + quad*4 + r;
                PQ[(long)g0*256 + half*128 + col] = f2bf(acc0[t][r] + bv);
                PQ[(long)g1*256 + half*128 + col] = f2bf(acc1[t][r] + bv);
            }
        }
    }
}

// ---- fused per-layer update (folded stage-1, full-K staging, 5 segments) ----
__global__ __launch_bounds__(256, 2) void fused_update_k(
    const unsigned short* __restrict__ Hb,      // [50048][128]
    const unsigned short* __restrict__ u1t,     // [128][256] (U1^T; k cols 0..128 = U1a)
    const unsigned short* __restrict__ wt2l,    // [128][128] (W2@U1b)^T
    const unsigned short* __restrict__ u2t,     // [128][128]
    const unsigned short* __restrict__ w1abt,   // [256][128] next-layer, or null
    const float* __restrict__ c1l,              // [128] b2@U1b
    const int* __restrict__ cnt,
    const float* __restrict__ ub1, const float* __restrict__ ub2,
    const float* __restrict__ lng, const float* __restrict__ lnb,
    const float* __restrict__ mb1n,             // next-layer b1, or null
    unsigned short* __restrict__ u_in,          // x at stride 256 (read cols 0:128, write x')
    unsigned short* __restrict__ PQ,            // [50048][256] out (if w1abt)
    float* __restrict__ sumv)                   // [128] colsum out (if !w1abt)
{
    __shared__ unsigned short Bs[128][136];     // staged B (N=128 x K=128, +pad)
    __shared__ unsigned short buf[128][136];    // inter-stage A (wave-row-partitioned)
    int tid = threadIdx.x, wave = tid >> 6, lane = tid & 63;
    int cl = lane & 15, quad = lane >> 4;
    int row0 = blockIdx.x * 128;
    int wrow = wave * 32;
    int grow0 = row0 + wrow;
    floatx4 zero = {0.f,0.f,0.f,0.f};
    floatx4 acc0[8], acc1[8];

    short8 hA0[4], hA1[4], xA0[4], xA1[4];
    PRELOAD_A128(hA0, hA1, Hb, 128);
    PRELOAD_A128(xA0, xA1, u_in, 256);

    // ---------- stage A: u_hid = relu(x@U1a + Hb@W2U1b + mask*c1 + ub1) -> buf ----------
    ZACC();
    STAGE_BF(u1t, 256);   MFMA_R4(xA0, xA1);
    STAGE_BF(wt2l, 128);  MFMA_R4(hA0, hA1);
    {
        float mask0[4], mask1[4];
        #pragma unroll
        for (int r = 0; r < 4; ++r) {
            mask0[r] = (cnt[grow0 + quad*4 + r] > 0) ? 1.f : 0.f;
            mask1[r] = (cnt[grow0 + 16 + quad*4 + r] > 0) ? 1.f : 0.f;
        }
        #pragma unroll
        for (int t = 0; t < 8; ++t) {
            int col = t*16 + cl;
            float bv = ub1[col], cv = c1l[col];
            #pragma unroll
            for (int r = 0; r < 4; ++r) {
                buf[wrow + quad*4 + r][col]      = f2bf(fmaxf(acc0[t][r] + mask0[r]*cv + bv, 0.f));
                buf[wrow + 16 + quad*4 + r][col] = f2bf(fmaxf(acc1[t][r] + mask1[r]*cv + bv, 0.f));
            }
        }
    }

    // ---------- stage B: y = u_hid@U2 + ub2 ; x' = relu(LN(y)*g+b) -> global + buf ----------
    ZACC();
    STAGE_BF(u2t, 128);   MFMA_L4();
    float colacc[8];
    {
        float rs0[4] = {0,0,0,0}, rq0[4] = {0,0,0,0}, rs1[4] = {0,0,0,0}, rq1[4] = {0,0,0,0};
        #pragma unroll
        for (int t = 0; t < 8; ++t) {
            float bv = ub2[t*16 + cl];
            #pragma unroll
            for (int r = 0; r < 4; ++r) {
                acc0[t][r] += bv; rs0[r] += acc0[t][r]; rq0[r] += acc0[t][r]*acc0[t][r];
                acc1[t][r] += bv; rs1[r] += acc1[t][r]; rq1[r] += acc1[t][r]*acc1[t][r];
            }
        }
        #pragma unroll
        for (int o = 1; o < 16; o <<= 1) {
            #pragma unroll
            for (int r = 0; r < 4; ++r) {
                rs0[r] += __shfl_xor(rs0[r], o); rq0[r] += __shfl_xor(rq0[r], o);
                rs1[r] += __shfl_xor(rs1[r], o); rq1[r] += __shfl_xor(rq1[r], o);
            }
        }
        float mu0[4], iv0[4], mu1[4], iv1[4];
        #pragma unroll
        for (int r = 0; r < 4; ++r) {
            mu0[r] = rs0[r] * (1.f/128.f);
            iv0[r] = rsqrtf(rq0[r] * (1.f/128.f) - mu0[r]*mu0[r] + 1e-5f);
            mu1[r] = rs1[r] * (1.f/128.f);
            iv1[r] = rsqrtf(rq1[r] * (1.f/128.f) - mu1[r]*mu1[r] + 1e-5f);
        }
        #pragma unroll
        for (int t = 0; t < 8; ++t) {
            int col = t*16 + cl;
            float gv = lng[col], bb = lnb[col];
            float s = 0.f;
            #pragma unroll
            for (int r = 0; r < 4; ++r) {
                float y0 = fmaxf((acc0[t][r] - mu0[r]) * iv0[r] * gv + bb, 0.f);
                float y1 = fmaxf((acc1[t][r] - mu1[r]) * iv1[r] * gv + bb, 0.f);
                unsigned short h0 = f2bf(y0), h1 = f2bf(y1);
                int g0 = grow0 + quad*4 + r, g1 = grow0 + 16 + quad*4 + r;
                if (g0 < NNODES) { u_in[(long)g0*256 + col] = h0; s += y0; }
                if (g1 < NNODES) { u_in[(long)g1*256 + col] = h1; s += y1; }
                buf[wrow + quad*4 + r][col]      = h0;
                buf[wrow + 16 + quad*4 + r][col] = h1;
            }
            colacc[t] = s;
        }
    }

    if (w1abt) {
        // ---------- stage C: PQ' = x'@W1ab' (+b1' on P half) ----------
        #pragma unroll
        for (int half = 0; half < 2; ++half) {
            ZACC();
            STAGE_BF(w1abt + half*16384, 128);
            MFMA_L4();
            #pragma unroll
            for (int t = 0; t < 8; ++t) {
                int col = t*16 + cl;
                float bv = (half == 0) ? mb1n[col] : 0.f;
                #pragma unroll
                for (int r = 0; r < 4; ++r) {
                    int g0 = grow0 + quad*4 + r, g1 = grow0 + 16 + quad*4 + r;
                    PQ[(long)g0*256 + half*128 + col] = f2bf(acc0[t][r] + bv);
                    PQ[(long)g1*256 + half*128 + col] = f2bf(acc1[t][r] + bv);
                }
            }
        }
    } else {
        // ---------- last layer: block-reduce column sums of x' into sumv ----------
        #pragma unroll
        for (int t = 0; t < 8; ++t) {
            colacc[t] += __shfl_xor(colacc[t], 16);
            colacc[t] += __shfl_xor(colacc[t], 32);
        }
        float* red = (float*)&buf[0][0];
        __syncthreads();
        if (lane < 16) {
            #pragma unroll
            for (int t = 0; t < 8; ++t) red[wave*128 + t*16 + lane] = colacc[t];
        }
        __syncthreads();
        if (tid < 128) {
            float s = red[tid] + red[128 + tid] + red[256 + tid] + red[384 + tid];
            atomicAdd(&sumv[tid], s);
        }
    }
}

// ---- final tiny MLP on the mean (fp32) ----
__global__ __launch_bounds__(128) void final_k(
    const float* __restrict__ sum, const float* __restrict__ W1, const float* __restrict__ b1,
    const float* __restrict__ W2, const float* __restrict__ b2, float* __restrict__ out)
{
    __shared__ float gbuf[128], hbuf[128];
    int t = threadIdx.x;
    gbuf[t] = sum[t] * (1.f / 50000.f);
    __syncthreads();
    float a = b1[t];
    for (int k = 0; k < 128; ++k) a += gbuf[k] * W1[k*128 + t];
    hbuf[t] = fmaxf(a, 0.f);
    __syncthreads();
    float o = b2[t];
    for (int k = 0; k < 128; ++k) o += hbuf[k] * W2[k*128 + t];
    out[t] = o;
}

extern "C" void kernel_launch(void* const* d_in, const int* in_sizes, int n_in,
                              void* d_out, int out_size, void* d_ws, size_t ws_size,
                              hipStream_t stream)
{
    const float* node_feat = (const float*)d_in[0];
    const float* edge_attr = (const float*)d_in[1];
    const float* enc_W  = (const float*)d_in[2];
    const float* enc_b  = (const float*)d_in[3];
    const float* mlp_W1 = (const float*)d_in[4];
    const float* mlp_b1 = (const float*)d_in[5];
    const float* mlp_W2 = (const float*)d_in[6];
    const float* mlp_b2 = (const float*)d_in[7];
    const float* upd_W1 = (const float*)d_in[8];
    const float* upd_b1 = (const float*)d_in[9];
    const float* upd_W2 = (const float*)d_in[10];
    const float* upd_b2 = (const float*)d_in[11];
    const float* ln_g   = (const float*)d_in[12];
    const float* ln_b   = (const float*)d_in[13];
    const float* out_W1 = (const float*)d_in[14];
    const float* out_b1 = (const float*)d_in[15];
    const float* out_W2 = (const float*)d_in[16];
    const float* out_b2 = (const float*)d_in[17];
    const int* edge_index = (const int*)d_in[18];
    const int* e_src = edge_index;
    const int* e_dst = edge_index + NEDGES;

    // workspace layout (padded node rows = 50048; scan arrays padded to 50176)
    char* ws = (char*)d_ws;
    unsigned short* u_in = (unsigned short*)(ws + 0);          // [50048][256] bf16: [x | scratch]
    unsigned short* PQ   = (unsigned short*)(ws + 25624576);   // [50048][256] bf16: [P | Q]
    unsigned short* Hb   = (unsigned short*)(ws + 51249152);   // [50048][128] bf16
    unsigned int* sorted = (unsigned int*)(ws + 64061440);     // [800000] packed {bf16 ea | u16 src}
    float* sumv          = (float*)(ws + 70460928);            // [128] (adjacent to cnt: one memset)
    int* cnt             = (int*)(ws + 70461440);              // [50176]
    int* offs            = (int*)(ws + 70662144);              // [50176]
    int* btot            = (int*)(ws + 70862848);              // [64]
    unsigned short* wt   = (unsigned short*)(ws + 70863360);   // [3*WPL] bf16 weights
    unsigned short* wt2  = (unsigned short*)(ws + 71453184);   // [3*16384] bf16 (W2@U1b)^T
    float* c1f           = (float*)(ws + 71551488);            // [3*128] b2@U1b
    int* rank            = (int*)(ws + 71553024);              // [800000] edge rank in dst bucket

    hipMemsetAsync(sumv, 0, 512 + NPAD*4, stream);   // zeroes sumv + cnt in one launch
    cvt_weights<<<1152, 256, 0, stream>>>(mlp_W1, mlp_W2, upd_W1, upd_W2, wt);
    prep_k<<<3, 256, 0, stream>>>(wt, mlp_b2, wt2, c1f);
    hist_k<<<3125, 256, 0, stream>>>(e_dst, cnt, rank);
    scan1_k<<<49, 256, 0, stream>>>(cnt, offs, btot);
    scan23_k<<<49, 256, 0, stream>>>(btot, offs);
    place_k<<<3125, 256, 0, stream>>>(e_src, e_dst, edge_attr, offs, rank, sorted);

    // fused encoder + PQ0 (layer-0 weights)
    enc_pq_k<<<391, 256, 0, stream>>>(node_feat, enc_W, enc_b, wt, mlp_b1, u_in, PQ);

    for (int l = 0; l < 3; ++l) {
        const unsigned short* u1t = wt + l*WPL + 49152;    // [128][256]
        const unsigned short* u2t = wt + l*WPL + 81920;    // [128][128]
        // Hb = inv_deg * segsum(relu(P[dst]+Q[src]+ea*w1c))
        aggregate_k<<<6250, 512, 0, stream>>>(PQ, sorted, offs, cnt,
                                              mlp_W1 + (l*257 + 256)*128, Hb);
        // fused: u_hid (folded aggr) -> x' (LN) -> PQ for layer l+1 (or colsum on last layer)
        fused_update_k<<<391, 256, 0, stream>>>(
            Hb, u1t, wt2 + (long)l*16384, u2t,
            (l < 2) ? (wt + (l+1)*WPL) : nullptr,
            c1f + l*128, cnt,
            upd_b1 + l*128, upd_b2 + l*128,
            ln_g + l*128, ln_b + l*128,
            (l < 2) ? (mlp_b1 + (l+1)*128) : nullptr,
            u_in, PQ, sumv);
    }
    final_k<<<1, 128, 0, stream>>>(sumv, out_W1, out_b1, out_W2, out_b2, (float*)d_out);
}